// Round 4
// baseline (591.430 us; speedup 1.0000x reference)
//
#include <hip/hip_runtime.h>
#include <hip/hip_bf16.h>

#define NN      262144    // N = B*WIN_IN*NODES
#define EDGES   2097152
#define FEATD   16
#define HIDD    64
#define LSTMH   32
#define BATCH   64
#define WIN     32
#define WOUT    8
#define NCLS    10
#define ROWD    2048      // NODES*FEAT = B*WIN (both 2048)
#define KCHUNKS 8

#define NB      2048      // buckets: node >> 7
#define SH      8         // shards (by blockIdx&7) to cut counter contention
#define CAP     224       // per (shard,bucket) capacity; Poisson(128)+8.5 sigma

// ---- bucketize edges: bdata[(s*NB+b)*CAP + pos] = (r<<7)|(c&127) ----
__global__ void k_bucketize(const int* __restrict__ ei, int* __restrict__ bcnt,
                            int* __restrict__ bdata) {
    int s = blockIdx.x & (SH - 1);
    int stride = gridDim.x * blockDim.x;
    for (int e = blockIdx.x * blockDim.x + threadIdx.x; e < EDGES; e += stride) {
        int r = ei[e];
        int c = ei[EDGES + e];
        int b = c >> 7;
        int pos = atomicAdd(&bcnt[s * NB + b], 1);
        if (pos < CAP) bdata[(size_t)(s * NB + b) * CAP + pos] = (r << 7) | (c & 127);
    }
}

// ---- per-bucket degree -> dinv (LDS histogram, coalesced writes) ----
__global__ void k_bdeg(const int* __restrict__ bcnt, const int* __restrict__ bdata,
                       float* __restrict__ dinv) {
    __shared__ int hist[128];
    int b = blockIdx.x, tid = threadIdx.x;
    if (tid < 128) hist[tid] = 0;
    __syncthreads();
#pragma unroll
    for (int s = 0; s < SH; s++) {
        int len = bcnt[s * NB + b]; if (len > CAP) len = CAP;
        const int* base = bdata + (size_t)(s * NB + b) * CAP;
        for (int i = tid; i < len; i += blockDim.x)
            atomicAdd(&hist[base[i] & 127], 1);
    }
    __syncthreads();
    if (tid < 128) dinv[b * 128 + tid] = rsqrtf((float)hist[tid] + 1.0f);
}

// ---- bucket aggregation into LDS tile; fused self term (+b2,relu layer 2) ----
template<int LAYER>
__global__ void k_bagg(const int* __restrict__ bcnt, const int* __restrict__ bdata,
                       const float* __restrict__ dinv, const float* __restrict__ src,
                       const float* __restrict__ b2, float* __restrict__ out) {
    __shared__ float acc[128 * FEATD];   // 8 KB
    int b = blockIdx.x, tid = threadIdx.x;
    for (int l = tid; l < 128 * FEATD; l += blockDim.x) acc[l] = 0.f;
    __syncthreads();
#pragma unroll
    for (int s = 0; s < SH; s++) {
        int len = bcnt[s * NB + b]; if (len > CAP) len = CAP;
        const int* base = bdata + (size_t)(s * NB + b) * CAP;
        for (int i = tid; i < len; i += blockDim.x) {
            int v = base[i];
            int r = v >> 7;
            int co = v & 127;
            float sc = dinv[r];
            const float4* p = (const float4*)(src + (size_t)r * FEATD);
            float* a = acc + co * FEATD;
#pragma unroll
            for (int q = 0; q < 4; q++) {
                float4 t = p[q];
                atomicAdd(&a[q * 4 + 0], t.x * sc);
                atomicAdd(&a[q * 4 + 1], t.y * sc);
                atomicAdd(&a[q * 4 + 2], t.z * sc);
                atomicAdd(&a[q * 4 + 3], t.w * sc);
            }
        }
    }
    __syncthreads();
    for (int l = tid; l < 128 * FEATD; l += blockDim.x) {
        int n = b * 128 + (l >> 4);
        int f = l & 15;
        float dc = dinv[n];
        float v = acc[l] * dc + src[(size_t)n * FEATD + f] * dc * dc;
        if (LAYER == 2) v = fmaxf(v + b2[f], 0.f);
        out[(size_t)b * (128 * FEATD) + l] = v;
    }
}

// ---- fused MLP: hid = relu(in1@W1+b1) ; t2 = hid@W2 ----
__global__ void k_gcnmlp(const float* __restrict__ in1,
                         const float* __restrict__ W1, const float* __restrict__ b1,
                         const float* __restrict__ W2, float* __restrict__ t2) {
    __shared__ float sW1[FEATD * HIDD];
    __shared__ float sW2[HIDD * FEATD];
    __shared__ float sb1[HIDD];
    for (int l = threadIdx.x; l < FEATD * HIDD; l += blockDim.x) {
        sW1[l] = W1[l];
        sW2[l] = W2[l];
    }
    if (threadIdx.x < HIDD) sb1[threadIdx.x] = b1[threadIdx.x];
    __syncthreads();
    int n = blockIdx.x * blockDim.x + threadIdx.x;
    if (n >= NN) return;
    float in[FEATD];
    const float4* ax = (const float4*)(in1 + (size_t)n * FEATD);
#pragma unroll
    for (int q = 0; q < 4; q++) {
        float4 a = ax[q];
        in[q * 4 + 0] = a.x; in[q * 4 + 1] = a.y; in[q * 4 + 2] = a.z; in[q * 4 + 3] = a.w;
    }
    float out[FEATD];
#pragma unroll
    for (int c = 0; c < FEATD; c++) out[c] = 0.f;
#pragma unroll 8
    for (int j = 0; j < HIDD; j++) {
        float h = sb1[j];
#pragma unroll
        for (int f = 0; f < FEATD; f++) h += in[f] * sW1[f * HIDD + j];
        h = fmaxf(h, 0.f);
#pragma unroll
        for (int c = 0; c < FEATD; c++) out[c] += h * sW2[j * FEATD + c];
    }
    float4* o = (float4*)(t2 + (size_t)n * FEATD);
    o[0] = make_float4(out[0], out[1], out[2], out[3]);
    o[1] = make_float4(out[4], out[5], out[6], out[7]);
    o[2] = make_float4(out[8], out[9], out[10], out[11]);
    o[3] = make_float4(out[12], out[13], out[14], out[15]);
}

// ---- LSTM input GEMM: gxp[p][r][j] = sum_{k in chunk p} A[r][k]*Wih[j][k] ----
#define KT 32
__global__ void k_gemmA(const float* __restrict__ A, const float* __restrict__ Wih,
                        float* __restrict__ gxp) {
    __shared__ float As[64][KT + 1];
    __shared__ float Bs[128][KT + 1];
    int tid = threadIdx.x;
    int tx = tid & 15, ty = tid >> 4;
    float acc[4][8];
#pragma unroll
    for (int i = 0; i < 4; i++)
#pragma unroll
        for (int j = 0; j < 8; j++) acc[i][j] = 0.f;
    int row0 = blockIdx.x * 64;
    int k0 = blockIdx.y * (ROWD / KCHUNKS);
    for (int kk = 0; kk < ROWD / KCHUNKS; kk += KT) {
        for (int l = tid; l < 64 * KT / 4; l += 256) {
            int rr = l >> 3;
            int cc = (l & 7) * 4;
            float4 v = *(const float4*)&A[(size_t)(row0 + rr) * ROWD + k0 + kk + cc];
            As[rr][cc + 0] = v.x; As[rr][cc + 1] = v.y; As[rr][cc + 2] = v.z; As[rr][cc + 3] = v.w;
        }
        for (int l = tid; l < 128 * KT / 4; l += 256) {
            int rr = l >> 3;
            int cc = (l & 7) * 4;
            float4 v = *(const float4*)&Wih[(size_t)rr * ROWD + k0 + kk + cc];
            Bs[rr][cc + 0] = v.x; Bs[rr][cc + 1] = v.y; Bs[rr][cc + 2] = v.z; Bs[rr][cc + 3] = v.w;
        }
        __syncthreads();
#pragma unroll
        for (int k = 0; k < KT; k++) {
            float a[4], bb[8];
#pragma unroll
            for (int i = 0; i < 4; i++) a[i] = As[ty * 4 + i][k];
#pragma unroll
            for (int j = 0; j < 8; j++) bb[j] = Bs[tx * 8 + j][k];
#pragma unroll
            for (int i = 0; i < 4; i++)
#pragma unroll
                for (int j = 0; j < 8; j++) acc[i][j] += a[i] * bb[j];
        }
        __syncthreads();
    }
    float* outp = gxp + (size_t)blockIdx.y * (ROWD * 128);
#pragma unroll
    for (int i = 0; i < 4; i++)
#pragma unroll
        for (int j = 0; j < 8; j++)
            outp[(size_t)(row0 + ty * 4 + i) * 128 + tx * 8 + j] = acc[i][j];
}

// ---- LSTM recurrence: one block per batch element ----
__global__ void k_lstm(const float* __restrict__ gxp, const float* __restrict__ Whh,
                       const float* __restrict__ bih, const float* __restrict__ bhh,
                       float* __restrict__ hseq) {
    __shared__ float sWhhT[LSTMH][4 * LSTMH];   // [k][j] = Whh[j][k]
    __shared__ float sh[LSTMH], sc[LSTMH], sg[4 * LSTMH];
    int b = blockIdx.x, j = threadIdx.x;
    for (int l = j; l < 4 * LSTMH * LSTMH; l += 4 * LSTMH) {
        int r = l >> 5, k = l & 31;
        sWhhT[k][r] = Whh[l];
    }
    float bias = bih[j] + bhh[j];
    if (j < LSTMH) { sh[j] = 0.f; sc[j] = 0.f; }
    __syncthreads();
    for (int t = 0; t < WIN; t++) {
        const float* g0 = gxp + (size_t)(b * WIN + t) * 128 + j;
        float g = bias;
#pragma unroll
        for (int p = 0; p < KCHUNKS; p++) g += g0[(size_t)p * ROWD * 128];
#pragma unroll
        for (int k = 0; k < LSTMH; k++) g += sWhhT[k][j] * sh[k];
        sg[j] = g;
        __syncthreads();
        if (j < LSTMH) {
            float ig = sg[j], fg = sg[32 + j], gg = sg[64 + j], og = sg[96 + j];
            float c = sc[j];
            float si = 1.f / (1.f + __expf(-ig));
            float sf = 1.f / (1.f + __expf(-fg));
            float so = 1.f / (1.f + __expf(-og));
            c = sf * c + si * tanhf(gg);
            float h = so * tanhf(c);
            sc[j] = c; sh[j] = h;
            if (t >= WIN - WOUT)
                hseq[(size_t)(b * WOUT + (t - (WIN - WOUT))) * LSTMH + j] = h;
        }
        __syncthreads();
    }
}

// ---- FC head: (512 rows) 32 -> 16 relu -> 10 ----
__global__ void k_fc(const float* __restrict__ hseq, const float* __restrict__ Wfc1,
                     const float* __restrict__ bfc1, const float* __restrict__ Wfc2,
                     const float* __restrict__ bfc2, float* __restrict__ out) {
    __shared__ float sW1[16 * 32], sb1[16], sW2[10 * 16], sb2[10];
    int tid = threadIdx.x;
    for (int l = tid; l < 16 * 32; l += blockDim.x) sW1[l] = Wfc1[l];
    if (tid < 16) sb1[tid] = bfc1[tid];
    for (int l = tid; l < 160; l += blockDim.x) sW2[l] = Wfc2[l];
    if (tid < 10) sb2[tid] = bfc2[tid];
    __syncthreads();
    int r = blockIdx.x * blockDim.x + tid;
    if (r >= BATCH * WOUT) return;
    float h[32];
#pragma unroll
    for (int k = 0; k < 32; k++) h[k] = hseq[(size_t)r * 32 + k];
    float hid[16];
#pragma unroll
    for (int j = 0; j < 16; j++) {
        float v = sb1[j];
#pragma unroll
        for (int k = 0; k < 32; k++) v += sW1[j * 32 + k] * h[k];
        hid[j] = fmaxf(v, 0.f);
    }
#pragma unroll
    for (int c = 0; c < NCLS; c++) {
        float v = sb2[c];
#pragma unroll
        for (int j = 0; j < 16; j++) v += sW2[c * 16 + j] * hid[j];
        out[(size_t)r * NCLS + c] = v;
    }
}

extern "C" void kernel_launch(void* const* d_in, const int* in_sizes, int n_in,
                              void* d_out, int out_size, void* d_ws, size_t ws_size,
                              hipStream_t stream) {
    const float* x    = (const float*)d_in[0];
    const int*   ei   = (const int*)d_in[1];
    const float* W1   = (const float*)d_in[2];
    const float* b1   = (const float*)d_in[3];
    const float* W2   = (const float*)d_in[4];
    const float* b2   = (const float*)d_in[5];
    const float* Wih  = (const float*)d_in[6];
    const float* Whh  = (const float*)d_in[7];
    const float* bih  = (const float*)d_in[8];
    const float* bhh  = (const float*)d_in[9];
    const float* Wfc1 = (const float*)d_in[10];
    const float* bfc1 = (const float*)d_in[11];
    const float* Wfc2 = (const float*)d_in[12];
    const float* bfc2 = (const float*)d_in[13];
    float* out = (float*)d_out;

    float* ws   = (float*)d_ws;
    float* dinv = ws;                                  // NN floats (1 MB)
    int*   bcnt = (int*)(dinv + NN);                   // SH*NB ints (64 KB)
    int*   bdata= bcnt + SH * NB;                      // SH*NB*CAP ints (14 MB)
    float* bufA = (float*)(bdata + (size_t)SH * NB * CAP); // NN*16 (16 MB)
    float* bufB = bufA + (size_t)NN * FEATD;           // NN*16 (16 MB)
    float* hseq = bufB + (size_t)NN * FEATD;           // 64*8*32

    hipMemsetAsync(bcnt, 0, SH * NB * sizeof(int), stream);
    k_bucketize<<<2048, 256, 0, stream>>>(ei, bcnt, bdata);
    k_bdeg<<<NB, 256, 0, stream>>>(bcnt, bdata, dinv);

    k_bagg<1><<<NB, 256, 0, stream>>>(bcnt, bdata, dinv, x, b2, bufA);
    k_gcnmlp<<<NN / 256, 256, 0, stream>>>(bufA, W1, b1, W2, bufB);
    k_bagg<2><<<NB, 256, 0, stream>>>(bcnt, bdata, dinv, bufB, b2, bufA);

    dim3 gg(ROWD / 64, KCHUNKS);
    k_gemmA<<<gg, 256, 0, stream>>>(bufA, Wih, bufB);
    k_lstm<<<BATCH, 128, 0, stream>>>(bufB, Whh, bih, bhh, hseq);
    k_fc<<<2, 256, 0, stream>>>(hseq, Wfc1, bfc1, Wfc2, bfc2, out);
}

// Round 6
// 587.012 us; speedup vs baseline: 1.0075x; 1.0075x over previous
//
#include <hip/hip_runtime.h>
#include <hip/hip_bf16.h>

#define NN      262144    // N = B*WIN_IN*NODES
#define EDGES   2097152
#define FEATD   16
#define HIDD    64
#define LSTMH   32
#define BATCH   64
#define WIN     32
#define WOUT    8
#define NCLS    10
#define ROWD    2048      // NODES*FEAT = B*WIN (both 2048)
#define KCHUNKS 8

#define NB      2048      // buckets: node >> 7
#define SH      8         // shards (by blockIdx&7) to cut counter contention
#define CAP     224       // per (shard,bucket) capacity; Poisson(128)+8.5 sigma

// ---- bucketize edges: bdata[(s*NB+b)*CAP + pos] = (r<<7)|(c&127) ----
__global__ void k_bucketize(const int* __restrict__ ei, int* __restrict__ bcnt,
                            int* __restrict__ bdata) {
    int s = blockIdx.x & (SH - 1);
    int stride = gridDim.x * blockDim.x;
    for (int e = blockIdx.x * blockDim.x + threadIdx.x; e < EDGES; e += stride) {
        int r = ei[e];
        int c = ei[EDGES + e];
        int b = c >> 7;
        int pos = atomicAdd(&bcnt[s * NB + b], 1);
        if (pos < CAP) bdata[(size_t)(s * NB + b) * CAP + pos] = (r << 7) | (c & 127);
    }
}

// ---- per-bucket degree -> dinv (LDS histogram, coalesced writes) ----
__global__ void k_bdeg(const int* __restrict__ bcnt, const int* __restrict__ bdata,
                       float* __restrict__ dinv) {
    __shared__ int hist[128];
    int b = blockIdx.x, tid = threadIdx.x;
    if (tid < 128) hist[tid] = 0;
    __syncthreads();
#pragma unroll
    for (int s = 0; s < SH; s++) {
        int len = bcnt[s * NB + b]; if (len > CAP) len = CAP;
        const int* base = bdata + (size_t)(s * NB + b) * CAP;
        for (int i = tid; i < len; i += blockDim.x)
            atomicAdd(&hist[base[i] & 127], 1);
    }
    __syncthreads();
    if (tid < 128) dinv[b * 128 + tid] = rsqrtf((float)hist[tid] + 1.0f);
}

// ---- bucket aggregation: 4 lanes per edge (lane q = float4 q of the row) ----
// 16 edges in flight per wave -> 4x memory-level parallelism vs 1-thread-per-edge.
template<int LAYER>
__global__ void __launch_bounds__(256)
k_bagg(const int* __restrict__ bcnt, const int* __restrict__ bdata,
       const float* __restrict__ dinv, const float* __restrict__ src,
       const float* __restrict__ b2, float* __restrict__ out) {
    __shared__ float acc[128 * FEATD];   // 8 KB
    int b = blockIdx.x, tid = threadIdx.x;
    for (int l = tid; l < 128 * FEATD; l += blockDim.x) acc[l] = 0.f;
    __syncthreads();
    int g = tid >> 2;        // 64 edge-groups per block
    int q = tid & 3;         // which float4 of the 16-float row
#pragma unroll
    for (int s = 0; s < SH; s++) {
        int len = bcnt[s * NB + b]; if (len > CAP) len = CAP;
        const int* base = bdata + (size_t)(s * NB + b) * CAP;
        for (int i = g; i < len; i += 64) {
            int v = base[i];                    // 4 lanes same word (merged)
            int r = v >> 7;
            int co = v & 127;
            float sc = dinv[r];
            float4 t = ((const float4*)(src + (size_t)r * FEATD))[q];
            float* a = acc + co * FEATD + q * 4;
            atomicAdd(&a[0], t.x * sc);
            atomicAdd(&a[1], t.y * sc);
            atomicAdd(&a[2], t.z * sc);
            atomicAdd(&a[3], t.w * sc);
        }
    }
    __syncthreads();
    for (int l = tid; l < 128 * FEATD; l += blockDim.x) {
        int n = b * 128 + (l >> 4);
        int f = l & 15;
        float dc = dinv[n];
        float v = acc[l] * dc + src[(size_t)n * FEATD + f] * dc * dc;
        if (LAYER == 2) v = fmaxf(v + b2[f], 0.f);
        out[(size_t)b * (128 * FEATD) + l] = v;
    }
}

// ---- fused MLP: hid = relu(in1@W1+b1) ; t2 = hid@W2 ----
__global__ void k_gcnmlp(const float* __restrict__ in1,
                         const float* __restrict__ W1, const float* __restrict__ b1,
                         const float* __restrict__ W2, float* __restrict__ t2) {
    __shared__ float sW1[FEATD * HIDD];
    __shared__ float sW2[HIDD * FEATD];
    __shared__ float sb1[HIDD];
    for (int l = threadIdx.x; l < FEATD * HIDD; l += blockDim.x) {
        sW1[l] = W1[l];
        sW2[l] = W2[l];
    }
    if (threadIdx.x < HIDD) sb1[threadIdx.x] = b1[threadIdx.x];
    __syncthreads();
    int n = blockIdx.x * blockDim.x + threadIdx.x;
    if (n >= NN) return;
    float in[FEATD];
    const float4* ax = (const float4*)(in1 + (size_t)n * FEATD);
#pragma unroll
    for (int q = 0; q < 4; q++) {
        float4 a = ax[q];
        in[q * 4 + 0] = a.x; in[q * 4 + 1] = a.y; in[q * 4 + 2] = a.z; in[q * 4 + 3] = a.w;
    }
    float out[FEATD];
#pragma unroll
    for (int c = 0; c < FEATD; c++) out[c] = 0.f;
#pragma unroll 8
    for (int j = 0; j < HIDD; j++) {
        float h = sb1[j];
#pragma unroll
        for (int f = 0; f < FEATD; f++) h += in[f] * sW1[f * HIDD + j];
        h = fmaxf(h, 0.f);
#pragma unroll
        for (int c = 0; c < FEATD; c++) out[c] += h * sW2[j * FEATD + c];
    }
    float4* o = (float4*)(t2 + (size_t)n * FEATD);
    o[0] = make_float4(out[0], out[1], out[2], out[3]);
    o[1] = make_float4(out[4], out[5], out[6], out[7]);
    o[2] = make_float4(out[8], out[9], out[10], out[11]);
    o[3] = make_float4(out[12], out[13], out[14], out[15]);
}

// ---- LSTM input GEMM: gxp[p][r][j] = sum_{k in chunk p} A[r][k]*Wih[j][k] ----
#define KT 32
__global__ void k_gemmA(const float* __restrict__ A, const float* __restrict__ Wih,
                        float* __restrict__ gxp) {
    __shared__ float As[64][KT + 1];
    __shared__ float Bs[128][KT + 1];
    int tid = threadIdx.x;
    int tx = tid & 15, ty = tid >> 4;
    float acc[4][8];
#pragma unroll
    for (int i = 0; i < 4; i++)
#pragma unroll
        for (int j = 0; j < 8; j++) acc[i][j] = 0.f;
    int row0 = blockIdx.x * 64;
    int k0 = blockIdx.y * (ROWD / KCHUNKS);
    for (int kk = 0; kk < ROWD / KCHUNKS; kk += KT) {
        for (int l = tid; l < 64 * KT / 4; l += 256) {
            int rr = l >> 3;
            int cc = (l & 7) * 4;
            float4 v = *(const float4*)&A[(size_t)(row0 + rr) * ROWD + k0 + kk + cc];
            As[rr][cc + 0] = v.x; As[rr][cc + 1] = v.y; As[rr][cc + 2] = v.z; As[rr][cc + 3] = v.w;
        }
        for (int l = tid; l < 128 * KT / 4; l += 256) {
            int rr = l >> 3;
            int cc = (l & 7) * 4;
            float4 v = *(const float4*)&Wih[(size_t)rr * ROWD + k0 + kk + cc];
            Bs[rr][cc + 0] = v.x; Bs[rr][cc + 1] = v.y; Bs[rr][cc + 2] = v.z; Bs[rr][cc + 3] = v.w;
        }
        __syncthreads();
#pragma unroll
        for (int k = 0; k < KT; k++) {
            float a[4], bb[8];
#pragma unroll
            for (int i = 0; i < 4; i++) a[i] = As[ty * 4 + i][k];
#pragma unroll
            for (int j = 0; j < 8; j++) bb[j] = Bs[tx * 8 + j][k];
#pragma unroll
            for (int i = 0; i < 4; i++)
#pragma unroll
                for (int j = 0; j < 8; j++) acc[i][j] += a[i] * bb[j];
        }
        __syncthreads();
    }
    float* outp = gxp + (size_t)blockIdx.y * (ROWD * 128);
#pragma unroll
    for (int i = 0; i < 4; i++)
#pragma unroll
        for (int j = 0; j < 8; j++)
            outp[(size_t)(row0 + ty * 4 + i) * 128 + tx * 8 + j] = acc[i][j];
}

// ---- LSTM recurrence: one block per batch element ----
__global__ void k_lstm(const float* __restrict__ gxp, const float* __restrict__ Whh,
                       const float* __restrict__ bih, const float* __restrict__ bhh,
                       float* __restrict__ hseq) {
    __shared__ float sWhhT[LSTMH][4 * LSTMH];   // [k][j] = Whh[j][k]
    __shared__ float sh[LSTMH], sc[LSTMH], sg[4 * LSTMH];
    int b = blockIdx.x, j = threadIdx.x;
    for (int l = j; l < 4 * LSTMH * LSTMH; l += 4 * LSTMH) {
        int r = l >> 5, k = l & 31;
        sWhhT[k][r] = Whh[l];
    }
    float bias = bih[j] + bhh[j];
    if (j < LSTMH) { sh[j] = 0.f; sc[j] = 0.f; }
    __syncthreads();
    for (int t = 0; t < WIN; t++) {
        const float* g0 = gxp + (size_t)(b * WIN + t) * 128 + j;
        float g = bias;
#pragma unroll
        for (int p = 0; p < KCHUNKS; p++) g += g0[(size_t)p * ROWD * 128];
#pragma unroll
        for (int k = 0; k < LSTMH; k++) g += sWhhT[k][j] * sh[k];
        sg[j] = g;
        __syncthreads();
        if (j < LSTMH) {
            float ig = sg[j], fg = sg[32 + j], gg = sg[64 + j], og = sg[96 + j];
            float c = sc[j];
            float si = 1.f / (1.f + __expf(-ig));
            float sf = 1.f / (1.f + __expf(-fg));
            float so = 1.f / (1.f + __expf(-og));
            c = sf * c + si * tanhf(gg);
            float h = so * tanhf(c);
            sc[j] = c; sh[j] = h;
            if (t >= WIN - WOUT)
                hseq[(size_t)(b * WOUT + (t - (WIN - WOUT))) * LSTMH + j] = h;
        }
        __syncthreads();
    }
}

// ---- FC head: (512 rows) 32 -> 16 relu -> 10 ----
__global__ void k_fc(const float* __restrict__ hseq, const float* __restrict__ Wfc1,
                     const float* __restrict__ bfc1, const float* __restrict__ Wfc2,
                     const float* __restrict__ bfc2, float* __restrict__ out) {
    __shared__ float sW1[16 * 32], sb1[16], sW2[10 * 16], sb2[10];
    int tid = threadIdx.x;
    for (int l = tid; l < 16 * 32; l += blockDim.x) sW1[l] = Wfc1[l];
    if (tid < 16) sb1[tid] = bfc1[tid];
    for (int l = tid; l < 160; l += blockDim.x) sW2[l] = Wfc2[l];
    if (tid < 10) sb2[tid] = bfc2[tid];
    __syncthreads();
    int r = blockIdx.x * blockDim.x + tid;
    if (r >= BATCH * WOUT) return;
    float h[32];
#pragma unroll
    for (int k = 0; k < 32; k++) h[k] = hseq[(size_t)r * 32 + k];
    float hid[16];
#pragma unroll
    for (int j = 0; j < 16; j++) {
        float v = sb1[j];
#pragma unroll
        for (int k = 0; k < 32; k++) v += sW1[j * 32 + k] * h[k];
        hid[j] = fmaxf(v, 0.f);
    }
#pragma unroll
    for (int c = 0; c < NCLS; c++) {
        float v = sb2[c];
#pragma unroll
        for (int j = 0; j < 16; j++) v += sW2[c * 16 + j] * hid[j];
        out[(size_t)r * NCLS + c] = v;
    }
}

extern "C" void kernel_launch(void* const* d_in, const int* in_sizes, int n_in,
                              void* d_out, int out_size, void* d_ws, size_t ws_size,
                              hipStream_t stream) {
    const float* x    = (const float*)d_in[0];
    const int*   ei   = (const int*)d_in[1];
    const float* W1   = (const float*)d_in[2];
    const float* b1   = (const float*)d_in[3];
    const float* W2   = (const float*)d_in[4];
    const float* b2   = (const float*)d_in[5];
    const float* Wih  = (const float*)d_in[6];
    const float* Whh  = (const float*)d_in[7];
    const float* bih  = (const float*)d_in[8];
    const float* bhh  = (const float*)d_in[9];
    const float* Wfc1 = (const float*)d_in[10];
    const float* bfc1 = (const float*)d_in[11];
    const float* Wfc2 = (const float*)d_in[12];
    const float* bfc2 = (const float*)d_in[13];
    float* out = (float*)d_out;

    float* ws   = (float*)d_ws;
    float* dinv = ws;                                  // NN floats (1 MB)
    int*   bcnt = (int*)(dinv + NN);                   // SH*NB ints (64 KB)
    int*   bdata= bcnt + SH * NB;                      // SH*NB*CAP ints (14 MB)
    float* bufA = (float*)(bdata + (size_t)SH * NB * CAP); // NN*16 (16 MB)
    float* bufB = bufA + (size_t)NN * FEATD;           // NN*16 (16 MB)
    float* hseq = bufB + (size_t)NN * FEATD;           // 64*8*32

    hipMemsetAsync(bcnt, 0, SH * NB * sizeof(int), stream);
    k_bucketize<<<2048, 256, 0, stream>>>(ei, bcnt, bdata);
    k_bdeg<<<NB, 256, 0, stream>>>(bcnt, bdata, dinv);

    k_bagg<1><<<NB, 256, 0, stream>>>(bcnt, bdata, dinv, x, b2, bufA);
    k_gcnmlp<<<NN / 256, 256, 0, stream>>>(bufA, W1, b1, W2, bufB);
    k_bagg<2><<<NB, 256, 0, stream>>>(bcnt, bdata, dinv, bufB, b2, bufA);

    dim3 gg(ROWD / 64, KCHUNKS);
    k_gemmA<<<gg, 256, 0, stream>>>(bufA, Wih, bufB);
    k_lstm<<<BATCH, 128, 0, stream>>>(bufB, Whh, bih, bhh, hseq);
    k_fc<<<2, 256, 0, stream>>>(hseq, Wfc1, bfc1, Wfc2, bfc2, out);
}